// Round 4
// baseline (219.343 us; speedup 1.0000x reference)
//
#include <hip/hip_runtime.h>

#define B_ 2
#define H_ 16
#define S_ 2048
#define DM 1024
#define DK 64
#define NX (4096 * 1024)   // q/k/v element count
#define NW (1024 * 1024)   // W element count

typedef unsigned short u16;
typedef __attribute__((ext_vector_type(8))) short bf16x8;          // MFMA A/B frag
typedef __attribute__((ext_vector_type(8))) unsigned short u16x8;  // 16-byte unit
typedef __attribute__((ext_vector_type(4))) unsigned short u16x4;  // 8-byte unit
typedef __attribute__((ext_vector_type(2))) unsigned int u32x2;
typedef __attribute__((ext_vector_type(4))) unsigned int u32x4;
typedef __attribute__((ext_vector_type(4))) float f32x4;           // 16x16 C/D
typedef __attribute__((ext_vector_type(16))) float f32x16;         // 32x32 C/D

__device__ inline u16 f2bf(float f) {                       // RNE float->bf16
  union { float f; unsigned int u; } c; c.f = f;
  unsigned int u = c.u;
  u += 0x7fffu + ((u >> 16) & 1u);
  return (u16)(u >> 16);
}

__device__ inline u16x8 cvt8(const float* __restrict__ src) {
  const float4 a = *reinterpret_cast<const float4*>(src);
  const float4 b = *reinterpret_cast<const float4*>(src + 4);
  u16x8 r;
  r[0] = f2bf(a.x); r[1] = f2bf(a.y); r[2] = f2bf(a.z); r[3] = f2bf(a.w);
  r[4] = f2bf(b.x); r[5] = f2bf(b.y); r[6] = f2bf(b.z); r[7] = f2bf(b.w);
  return r;
}

__device__ inline void glds16(const u16* g, u16* l) {       // async global->LDS, 16B/lane
  __builtin_amdgcn_global_load_lds(
      (const __attribute__((address_space(1))) unsigned int*)g,
      (__attribute__((address_space(3))) unsigned int*)l, 16, 0, 0);
}

__device__ inline unsigned cvtpk(float lo, float hi) {      // pack 2xf32 -> 2xbf16 (RNE)
  unsigned r;
  asm("v_cvt_pk_bf16_f32 %0, %1, %2" : "=v"(r) : "v"(lo), "v"(hi));
  return r;
}

// permlane32_swap: a.hi-lanes <-> b.lo-lanes (lane l pairs with l^32).
#if __has_builtin(__builtin_amdgcn_permlane32_swap)
__device__ inline void plswap(unsigned& a, unsigned& b) {
  auto r = __builtin_amdgcn_permlane32_swap(a, b, false, false);
  a = r[0]; b = r[1];
}
#else
__device__ inline void plswap(unsigned& a, unsigned& b) {
  const unsigned pa = (unsigned)__shfl_xor((int)a, 32, 64);
  const unsigned pb = (unsigned)__shfl_xor((int)b, 32, 64);
  const bool hi = (threadIdx.x & 32) != 0;
  const unsigned na = hi ? pb : a;
  const unsigned nb = hi ? b : pa;
  a = na; b = nb;
}
#endif

// ---------------------------------------------------------------------------
// Prepass: fp32 -> bf16 once per tensor.
// ---------------------------------------------------------------------------
__global__ __launch_bounds__(256) void cvt_kernel(
    const float* __restrict__ q, const float* __restrict__ k, const float* __restrict__ v,
    const float* __restrict__ Wq, const float* __restrict__ Wk, const float* __restrict__ Wv,
    u16* __restrict__ Xq, u16* __restrict__ Xk, u16* __restrict__ Xv,
    u16* __restrict__ Wqb, u16* __restrict__ Wkb, u16* __restrict__ Wvb)
{
  const int t = blockIdx.y;
  const float* src = (t == 0) ? q : (t == 1) ? k : (t == 2) ? v
                   : (t == 3) ? Wq : (t == 4) ? Wk : Wv;
  u16* dst = (t == 0) ? Xq : (t == 1) ? Xk : (t == 2) ? Xv
           : (t == 3) ? Wqb : (t == 4) ? Wkb : Wvb;
  const int n = (t < 3) ? NX : NW;
  const int idx = (blockIdx.x * 256 + threadIdx.x) * 8;
  if (idx >= n) return;
  *reinterpret_cast<u16x8*>(&dst[idx]) = cvt8(&src[idx]);
}

// ---------------------------------------------------------------------------
// Projection: Y = X @ W^T + b (bf16, m97-style). ALL outputs [bh][s][d]
// (coalesced stores). z=0 (Q) pre-scaled by (1/sqrt(Dk))*log2(e) for exp2.
// ---------------------------------------------------------------------------
__global__ __launch_bounds__(256) void proj_kernel(
    const u16* __restrict__ Xq, const u16* __restrict__ Xk, const u16* __restrict__ Xv,
    const u16* __restrict__ Wqb, const u16* __restrict__ Wkb, const u16* __restrict__ Wvb,
    const float* __restrict__ bq, const float* __restrict__ bk, const float* __restrict__ bv,
    u16* __restrict__ Qh, u16* __restrict__ Kh, u16* __restrict__ Vh)
{
  const int z = blockIdx.z;
  const u16* X      = (z == 0) ? Xq : (z == 1) ? Xk : Xv;
  const u16* W      = (z == 0) ? Wqb : (z == 1) ? Wkb : Wvb;
  const float* bias = (z == 0) ? bq : (z == 1) ? bk : bv;
  u16* out          = (z == 0) ? Qh : (z == 1) ? Kh : Vh;
  const float scale = (z == 0) ? 0.18033688f : 1.0f;   // 0.125 * log2(e)

  __shared__ __align__(16) u16 Xs[128 * 32];   // unpadded: required by global_load_lds
  __shared__ __align__(16) u16 Ws[128 * 32];

  const int tid = threadIdx.x;
  const int lane = tid & 63;
  const int w = tid >> 6;
  const int wy = w >> 1, wx = w & 1;
  const int m0 = blockIdx.y * 128;
  const int n0 = blockIdx.x * 128;
  const int ml = lane & 15;
  const int qd = lane >> 4;

  f32x4 acc[4][4] = {};

  for (int kb = 0; kb < DM; kb += 32) {
    __syncthreads();
    #pragma unroll
    for (int p = 0; p < 2; ++p) {
      const int c = p * 4 + w;                  // chunk: 16 rows x 32 cols = 1 KiB
      const int row = c * 16 + (lane >> 2);
      const int col = kb + (lane & 3) * 8;
      glds16(&X[(size_t)(m0 + row) * DM + col], &Xs[c * 512]);
      glds16(&W[(size_t)(n0 + row) * DM + col], &Ws[c * 512]);
    }
    __syncthreads();
    bf16x8 a[4], bfr[4];
    #pragma unroll
    for (int i = 0; i < 4; ++i)
      a[i] = *reinterpret_cast<const bf16x8*>(&Xs[(wy * 64 + i * 16 + ml) * 32 + qd * 8]);
    #pragma unroll
    for (int j = 0; j < 4; ++j)
      bfr[j] = *reinterpret_cast<const bf16x8*>(&Ws[(wx * 64 + j * 16 + ml) * 32 + qd * 8]);
    #pragma unroll
    for (int i = 0; i < 4; ++i)
      #pragma unroll
      for (int j = 0; j < 4; ++j)
        acc[i][j] = __builtin_amdgcn_mfma_f32_16x16x32_bf16(a[i], bfr[j], acc[i][j], 0, 0, 0);
  }

  #pragma unroll
  for (int j = 0; j < 4; ++j) {
    const int n = n0 + wx * 64 + j * 16 + ml;
    const float badd = bias[n];
    const int h = n >> 6, d = n & 63;
    #pragma unroll
    for (int i = 0; i < 4; ++i) {
      #pragma unroll
      for (int r = 0; r < 4; ++r) {
        const int m = m0 + wy * 64 + i * 16 + qd * 4 + r;
        const int bi = m >> 11, s = m & 2047;
        out[((bi * H_ + h) * S_ + s) * DK + d] = f2bf((acc[i][j][r] + badd) * scale);
      }
    }
  }
}

// ---------------------------------------------------------------------------
// Vh[bh][s][d] -> Vt[bh][d][s]  (64x64 LDS tile transpose, coalesced both ways)
// ---------------------------------------------------------------------------
__global__ __launch_bounds__(256) void transpose_kernel(
    const u16* __restrict__ Vh, u16* __restrict__ Vt)
{
  __shared__ __align__(16) u16 T[64 * 72];
  const int t = threadIdx.x;
  const int st = blockIdx.x, bh = blockIdx.y;
  {
    const int r = t >> 2, c = (t & 3) * 16;
    const u16* src = &Vh[((size_t)bh * S_ + st * 64 + r) * DK + c];
    *reinterpret_cast<u16x8*>(&T[r * 72 + c])     = *reinterpret_cast<const u16x8*>(src);
    *reinterpret_cast<u16x8*>(&T[r * 72 + c + 8]) = *reinterpret_cast<const u16x8*>(src + 8);
  }
  __syncthreads();
  {
    const int d = t >> 2, s0 = (t & 3) * 16;
    u16x8 a, b;
    #pragma unroll
    for (int i = 0; i < 8; ++i) a[i] = T[(s0 + i) * 72 + d];
    #pragma unroll
    for (int i = 0; i < 8; ++i) b[i] = T[(s0 + 8 + i) * 72 + d];
    u16* dst = &Vt[((size_t)bh * DK + d) * S_ + st * 64 + s0];
    *reinterpret_cast<u16x8*>(dst)     = a;
    *reinterpret_cast<u16x8*>(dst + 8) = b;
  }
}

// ---------------------------------------------------------------------------
// Flash causal attention, 32x32x16 MFMA, QBLK=128, KVBLK=64. 4 waves.
// R4 change: LDS cut 33.3KB -> 24.5KB so TWO balanced blocks co-reside per CU
// (R0-R3 evidence: usable-LDS occupancy cap ~55-64KB; >32KB -> 1 block/CU and
// blocks serialize; this was the 4000-cyc/iter mystery stall).
//   - K: double-buffered via global_load_lds (16KB).
//   - V: SINGLE buffer (8KB), reg-staged (T14): load V(t+1) global->reg at
//     loop top (linear coalesced src), publish regs->LDS via swizzled
//     ds_write_b128 after the tail barrier. Both-sides rule: linear global +
//     swizzled write + swizzled read.
//   - One vmcnt(0) per iter AFTER the compute barrier: every load has the full
//     compute phase (~1000cyc >> L2 latency) in flight.
//   - Compute/softmax/PV/decode/epilogue: identical to R3.
// ---------------------------------------------------------------------------
__global__ __launch_bounds__(256) void attn_kernel(
    const u16* __restrict__ Qh, const u16* __restrict__ Kh,
    const u16* __restrict__ Vt, float* __restrict__ out)
{
  __shared__ __align__(16) u16 Ks[2][64 * 64];   // [buf][key][dim]  (swizzled)
  __shared__ __align__(16) u16 Vs[64 * 64];      // [dim][key]       (swizzled)
  __shared__ float Ls[4][32];                    // per-wave 1/l

  const int tid  = threadIdx.x;
  const int lane = tid & 63;
  const int w    = tid >> 6;
  const int l31  = lane & 31, hi = lane >> 5;
  const int x7   = l31 & 7;

  // decode: xcd = fid&7 (4 heads per XCD); qt pairing f(x)+f(x+8)=15, long first
  const int fid = blockIdx.x;
  const int bh  = (fid & 7) * 4 + ((fid >> 3) & 3);
  const int qtl = fid >> 5;
  const int qt  = (qtl < 8) ? (15 - 2 * qtl) : (2 * (qtl - 8));
  const int b   = bh >> 4, h = bh & 15;
  const int R0  = qt * 128;
  const int nt  = 2 * qt + 2;

  // Q as B-operand: B[k = s*16 + hi*8 + e][n = qrow = l31]
  bf16x8 qa[4];
  {
    const u16* qp = &Qh[((size_t)bh * S_ + R0 + w * 32 + l31) * DK + hi * 8];
    #pragma unroll
    for (int s = 0; s < 4; ++s)
      qa[s] = *reinterpret_cast<const bf16x8*>(qp + s * 16);
  }
  asm volatile("s_waitcnt vmcnt(0)" ::: "memory");   // clean vmcnt bookkeeping

  // K staging (glds): chunk c -> LDS (row=c>>3, unit c&7); src unit=(c&7)^(row&7)
  const u16* kb0 = Kh + (size_t)bh * S_ * DK;
  const u16* vb0 = Vt + (size_t)bh * DK * S_;
  const int r0 = tid >> 3, r1 = r0 + 32;
  const int cs = (tid & 7) ^ (r0 & 7);             // (r1&7)==(r0&7)
  const u16* sK0 = kb0 + r0 * DK + cs * 8;         // +4096/tile (64 key rows)
  const u16* sK1 = kb0 + r1 * DK + cs * 8;

  // V staging (reg): LINEAR global source (coalesced), swizzled ds_write dest
  const int vu = tid & 7;
  const int vswz = (vu ^ (r0 & 7)) * 8;            // (r1&7)==(r0&7)
  const u16* sV0 = vb0 + (size_t)r0 * S_ + vu * 8; // +64/tile (64 keys)
  const u16* sV1 = vb0 + (size_t)r1 * S_ + vu * 8;
  u16* vd0 = &Vs[r0 * 64 + vswz];
  u16* vd1 = &Vs[r1 * 64 + vswz];

  f32x16 oacc0 = {}, oacc1 = {};
  float lsum = 0.f;

  // prologue: V(0) -> regs, K(0) -> Ks[0]
  u16x8 vreg0 = *reinterpret_cast<const u16x8*>(sV0);
  u16x8 vreg1 = *reinterpret_cast<const u16x8*>(sV1);
  glds16(sK0, &Ks[0][tid * 8]);
  glds16(sK1, &Ks[0][2048 + tid * 8]);
  sK0 += 4096; sK1 += 4096; sV0 += 64; sV1 += 64;
  asm volatile("s_waitcnt vmcnt(0)" ::: "memory");

  int cur = 0;
  for (int t = 0; t < nt; ++t) {
    // A: publish V(t) regs -> Vs (swizzled write; prev readers done at tail barrier)
    *reinterpret_cast<u16x8*>(vd0) = vreg0;
    *reinterpret_cast<u16x8*>(vd1) = vreg1;
    // B: prefetch t+1 (V->regs, K->Ks[cur^1]); in flight through compute(t)
    if (t + 1 < nt) {
      vreg0 = *reinterpret_cast<const u16x8*>(sV0);
      vreg1 = *reinterpret_cast<const u16x8*>(sV1);
      glds16(sK0, &Ks[cur ^ 1][tid * 8]);
      glds16(sK1, &Ks[cur ^ 1][2048 + tid * 8]);
      sK0 += 4096; sK1 += 4096; sV0 += 64; sV1 += 64;
    }
    asm volatile("s_waitcnt lgkmcnt(0)" ::: "memory");  // V writes visible
    __builtin_amdgcn_s_barrier();
    asm volatile("" ::: "memory");

    const u16* Kb = Ks[cur];

    // causal geometry (wave-uniform): base = wave rowbase - tile keybase
    const int base  = R0 + w * 32 - t * 64;
    const int ksmax = (base + 31) >> 5;              // subtile ks live iff ks<=ksmax
    const int ksm   = (ksmax > 1) ? 1 : ksmax;

    if (ksm >= 0) {
      // ---- QK^T: S^T[key][qrow], 2 key-subtiles x 4 k-steps of 32x32x16
      f32x16 sfr[2];
      __builtin_amdgcn_s_setprio(1);
      #pragma unroll
      for (int ks = 0; ks < 2; ++ks) {
        if (ks > ksm) break;
        const int rb = (ks * 32 + l31) * 64;
        f32x16 sf = {};
        #pragma unroll
        for (int s = 0; s < 4; ++s) {
          const bf16x8 af = *reinterpret_cast<const bf16x8*>(
              &Kb[rb + ((2 * s + hi) ^ x7) * 8]);
          sf = __builtin_amdgcn_mfma_f32_32x32x16_bf16(af, qa[s], sf, 0, 0, 0);
        }
        sfr[ks] = sf;
      }
      __builtin_amdgcn_s_setprio(0);

      // ---- softmax (per-lane: lane owns qrow l31's scores) + pack
      unsigned pku[2][4][2];                         // [ks][m][word]
      #pragma unroll
      for (int ks = 0; ks < 2; ++ks) {
        if (ks > ksm) break;
        const int Dg = base + l31 - 32 * ks - 4 * hi;   // per-lane causal bound
        const bool full = (base >= 32 * ks + 31);       // wave-uniform: no mask
        float e[16];
        #pragma unroll
        for (int r = 0; r < 16; ++r) {
          const int rk = (r & 3) + 8 * (r >> 2);        // kloc minus 4*hi
          const float ex = __builtin_amdgcn_exp2f(sfr[ks][r]);
          e[r] = (full || rk <= Dg) ? ex : 0.f;
        }
        float a01 = 0.f;
        #pragma unroll
        for (int r = 0; r < 16; ++r) a01 += e[r];
        lsum += a01;
        #pragma unroll
        for (int m = 0; m < 4; ++m) {
          pku[ks][m][0] = cvtpk(e[4 * m], e[4 * m + 1]);
          pku[ks][m][1] = cvtpk(e[4 * m + 2], e[4 * m + 3]);
        }
      }

      // ---- PV: O[qrow][dim] += P x V. A-frags built in-register via swaps.
      const int smax = 2 * ksm + 1;
      #pragma unroll
      for (int s = 0; s < 4; ++s) {
        if (s > smax) break;
        const int ks = s >> 1, p = s & 1;
        unsigned w0 = pku[ks][2 * p][0],     w1v = pku[ks][2 * p][1];
        unsigned w2 = pku[ks][2 * p + 1][0], w3  = pku[ks][2 * p + 1][1];
        plswap(w0, w2);                              // -> words 0,2
        plswap(w1v, w3);                             // -> words 1,3
        u32x4 paw; paw[0] = w0; paw[1] = w1v; paw[2] = w2; paw[3] = w3;
        const bf16x8 pa = *reinterpret_cast<const bf16x8*>(&paw);
        const int uv = ((2 * s + hi) ^ x7) * 8;
        const bf16x8 vb0f = *reinterpret_cast<const bf16x8*>(&Vs[l31 * 64 + uv]);
        const bf16x8 vb1f = *reinterpret_cast<const bf16x8*>(&Vs[(32 + l31) * 64 + uv]);
        __builtin_amdgcn_s_setprio(1);
        oacc0 = __builtin_amdgcn_mfma_f32_32x32x16_bf16(pa, vb0f, oacc0, 0, 0, 0);
        oacc1 = __builtin_amdgcn_mfma_f32_32x32x16_bf16(pa, vb1f, oacc1, 0, 0, 0);
        __builtin_amdgcn_s_setprio(0);
      }
    }

    asm volatile("" ::: "memory");
    __builtin_amdgcn_s_barrier();                    // Ks[cur]/Vs free for re-stage
    asm volatile("s_waitcnt vmcnt(0)" ::: "memory"); // t+1 loads landed (flew over E)
    cur ^= 1;
  }

  // epilogue: qrow sums live per-lane (col side); redistribute via tiny LDS
  const float lt = lsum + __shfl_xor(lsum, 32, 64);
  if (hi == 0) Ls[w][l31] = 1.0f / lt;
  // oacc row r -> qrow-within-32 = (r&3)+8*(r>>2)+4*hi ; col = dim = ds*32+l31
  #pragma unroll
  for (int r = 0; r < 16; ++r) {
    const int rq = (r & 3) + 8 * (r >> 2) + 4 * hi;
    const float inv = Ls[w][rq];
    const int srow = R0 + w * 32 + rq;
    float* op = &out[(size_t)(b * S_ + srow) * DM + h * DK + l31];
    op[0]  = oacc0[r] * inv;
    op[32] = oacc1[r] * inv;
  }
}

extern "C" void kernel_launch(void* const* d_in, const int* in_sizes, int n_in,
                              void* d_out, int out_size, void* d_ws, size_t ws_size,
                              hipStream_t stream) {
  // inputs: q,k,v,mask,Wq,bq,Wk,bk,Wv,bv — fp32 (mask int32, unused)
  const float* q  = (const float*)d_in[0];
  const float* k  = (const float*)d_in[1];
  const float* v  = (const float*)d_in[2];
  const float* Wq = (const float*)d_in[4];
  const float* bq = (const float*)d_in[5];
  const float* Wk = (const float*)d_in[6];
  const float* bk = (const float*)d_in[7];
  const float* Wv = (const float*)d_in[8];
  const float* bv = (const float*)d_in[9];

  u16* Xq  = (u16*)d_ws;          // 8 MB each for X*, 2 MB each for W*
  u16* Xk  = Xq + NX;
  u16* Xv  = Xk + NX;
  u16* Wqb = Xv + NX;
  u16* Wkb = Wqb + NW;
  u16* Wvb = Wkb + NW;
  u16* Qh  = Wvb + NW;            // [bh][s][d]
  u16* Kh  = Qh + NX;             // [bh][s][d]
  u16* Vh  = Kh + NX;             // [bh][s][d]
  u16* Vt  = Xq;                  // [bh][d][s] — aliases Xq (dead after proj)

  cvt_kernel<<<dim3(NX / (256 * 8), 6), 256, 0, stream>>>(
      q, k, v, Wq, Wk, Wv, Xq, Xk, Xv, Wqb, Wkb, Wvb);
  proj_kernel<<<dim3(DM / 128, (B_ * S_) / 128, 3), 256, 0, stream>>>(
      Xq, Xk, Xv, Wqb, Wkb, Wvb, bq, bk, bv, Qh, Kh, Vh);
  transpose_kernel<<<dim3(S_ / 64, B_ * H_), 256, 0, stream>>>(Vh, Vt);
  attn_kernel<<<dim3(512), 256, 0, stream>>>(
      Qh, Kh, Vt, (float*)d_out);
}

// Round 6
// 219.021 us; speedup vs baseline: 1.0015x; 1.0015x over previous
//
#include <hip/hip_runtime.h>

#define B_ 2
#define H_ 16
#define S_ 2048
#define DM 1024
#define DK 64
#define NX (4096 * 1024)   // q/k/v element count
#define NW (1024 * 1024)   // W element count

typedef unsigned short u16;
typedef __attribute__((ext_vector_type(8))) short bf16x8;          // MFMA A/B frag
typedef __attribute__((ext_vector_type(8))) unsigned short u16x8;  // 16-byte unit
typedef __attribute__((ext_vector_type(4))) unsigned short u16x4;  // 8-byte unit
typedef __attribute__((ext_vector_type(4))) unsigned int u32x4;
typedef __attribute__((ext_vector_type(4))) float f32x4;           // 16x16 C/D
typedef __attribute__((ext_vector_type(16))) float f32x16;         // 32x32 C/D

__device__ inline u16 f2bf(float f) {                       // RNE float->bf16
  union { float f; unsigned int u; } c; c.f = f;
  unsigned int u = c.u;
  u += 0x7fffu + ((u >> 16) & 1u);
  return (u16)(u >> 16);
}

__device__ inline u16x8 cvt8(const float* __restrict__ src) {
  const float4 a = *reinterpret_cast<const float4*>(src);
  const float4 b = *reinterpret_cast<const float4*>(src + 4);
  u16x8 r;
  r[0] = f2bf(a.x); r[1] = f2bf(a.y); r[2] = f2bf(a.z); r[3] = f2bf(a.w);
  r[4] = f2bf(b.x); r[5] = f2bf(b.y); r[6] = f2bf(b.z); r[7] = f2bf(b.w);
  return r;
}

__device__ inline void glds16(const u16* g, u16* l) {       // async global->LDS, 16B/lane
  __builtin_amdgcn_global_load_lds(
      (const __attribute__((address_space(1))) unsigned int*)g,
      (__attribute__((address_space(3))) unsigned int*)l, 16, 0, 0);
}

__device__ inline unsigned cvtpk(float lo, float hi) {      // pack 2xf32 -> 2xbf16 (RNE)
  unsigned r;
  asm("v_cvt_pk_bf16_f32 %0, %1, %2" : "=v"(r) : "v"(lo), "v"(hi));
  return r;
}

// permlane32_swap: a.hi-lanes <-> b.lo-lanes (lane l pairs with l^32).
#if __has_builtin(__builtin_amdgcn_permlane32_swap)
__device__ inline void plswap(unsigned& a, unsigned& b) {
  auto r = __builtin_amdgcn_permlane32_swap(a, b, false, false);
  a = r[0]; b = r[1];
}
#else
__device__ inline void plswap(unsigned& a, unsigned& b) {
  const unsigned pa = (unsigned)__shfl_xor((int)a, 32, 64);
  const unsigned pb = (unsigned)__shfl_xor((int)b, 32, 64);
  const bool hi = (threadIdx.x & 32) != 0;
  const unsigned na = hi ? pb : a;
  const unsigned nb = hi ? b : pa;
  a = na; b = nb;
}
#endif

// ---------------------------------------------------------------------------
// Prepass: fp32 -> bf16 once per tensor.
// ---------------------------------------------------------------------------
__global__ __launch_bounds__(256) void cvt_kernel(
    const float* __restrict__ q, const float* __restrict__ k, const float* __restrict__ v,
    const float* __restrict__ Wq, const float* __restrict__ Wk, const float* __restrict__ Wv,
    u16* __restrict__ Xq, u16* __restrict__ Xk, u16* __restrict__ Xv,
    u16* __restrict__ Wqb, u16* __restrict__ Wkb, u16* __restrict__ Wvb)
{
  const int t = blockIdx.y;
  const float* src = (t == 0) ? q : (t == 1) ? k : (t == 2) ? v
                   : (t == 3) ? Wq : (t == 4) ? Wk : Wv;
  u16* dst = (t == 0) ? Xq : (t == 1) ? Xk : (t == 2) ? Xv
           : (t == 3) ? Wqb : (t == 4) ? Wkb : Wvb;
  const int n = (t < 3) ? NX : NW;
  const int idx = (blockIdx.x * 256 + threadIdx.x) * 8;
  if (idx >= n) return;
  *reinterpret_cast<u16x8*>(&dst[idx]) = cvt8(&src[idx]);
}

// ---------------------------------------------------------------------------
// Projection: Y = X @ W^T + b (bf16, m97-style). ALL outputs [bh][s][d]
// (coalesced stores). z=0 (Q) pre-scaled by (1/sqrt(Dk))*log2(e) for exp2.
// ---------------------------------------------------------------------------
__global__ __launch_bounds__(256) void proj_kernel(
    const u16* __restrict__ Xq, const u16* __restrict__ Xk, const u16* __restrict__ Xv,
    const u16* __restrict__ Wqb, const u16* __restrict__ Wkb, const u16* __restrict__ Wvb,
    const float* __restrict__ bq, const float* __restrict__ bk, const float* __restrict__ bv,
    u16* __restrict__ Qh, u16* __restrict__ Kh, u16* __restrict__ Vh)
{
  const int z = blockIdx.z;
  const u16* X      = (z == 0) ? Xq : (z == 1) ? Xk : Xv;
  const u16* W      = (z == 0) ? Wqb : (z == 1) ? Wkb : Wvb;
  const float* bias = (z == 0) ? bq : (z == 1) ? bk : bv;
  u16* out          = (z == 0) ? Qh : (z == 1) ? Kh : Vh;
  const float scale = (z == 0) ? 0.18033688f : 1.0f;   // 0.125 * log2(e)

  __shared__ __align__(16) u16 Xs[128 * 32];   // unpadded: required by global_load_lds
  __shared__ __align__(16) u16 Ws[128 * 32];

  const int tid = threadIdx.x;
  const int lane = tid & 63;
  const int w = tid >> 6;
  const int wy = w >> 1, wx = w & 1;
  const int m0 = blockIdx.y * 128;
  const int n0 = blockIdx.x * 128;
  const int ml = lane & 15;
  const int qd = lane >> 4;

  f32x4 acc[4][4] = {};

  for (int kb = 0; kb < DM; kb += 32) {
    __syncthreads();
    #pragma unroll
    for (int p = 0; p < 2; ++p) {
      const int c = p * 4 + w;                  // chunk: 16 rows x 32 cols = 1 KiB
      const int row = c * 16 + (lane >> 2);
      const int col = kb + (lane & 3) * 8;
      glds16(&X[(size_t)(m0 + row) * DM + col], &Xs[c * 512]);
      glds16(&W[(size_t)(n0 + row) * DM + col], &Ws[c * 512]);
    }
    __syncthreads();
    bf16x8 a[4], bfr[4];
    #pragma unroll
    for (int i = 0; i < 4; ++i)
      a[i] = *reinterpret_cast<const bf16x8*>(&Xs[(wy * 64 + i * 16 + ml) * 32 + qd * 8]);
    #pragma unroll
    for (int j = 0; j < 4; ++j)
      bfr[j] = *reinterpret_cast<const bf16x8*>(&Ws[(wx * 64 + j * 16 + ml) * 32 + qd * 8]);
    #pragma unroll
    for (int i = 0; i < 4; ++i)
      #pragma unroll
      for (int j = 0; j < 4; ++j)
        acc[i][j] = __builtin_amdgcn_mfma_f32_16x16x32_bf16(a[i], bfr[j], acc[i][j], 0, 0, 0);
  }

  #pragma unroll
  for (int j = 0; j < 4; ++j) {
    const int n = n0 + wx * 64 + j * 16 + ml;
    const float badd = bias[n];
    const int h = n >> 6, d = n & 63;
    #pragma unroll
    for (int i = 0; i < 4; ++i) {
      #pragma unroll
      for (int r = 0; r < 4; ++r) {
        const int m = m0 + wy * 64 + i * 16 + qd * 4 + r;
        const int bi = m >> 11, s = m & 2047;
        out[((bi * H_ + h) * S_ + s) * DK + d] = f2bf((acc[i][j][r] + badd) * scale);
      }
    }
  }
}

// ---------------------------------------------------------------------------
// Vh[bh][s][d] -> Vt[bh][d][s]  (64x64 LDS tile transpose, coalesced both ways)
// ---------------------------------------------------------------------------
__global__ __launch_bounds__(256) void transpose_kernel(
    const u16* __restrict__ Vh, u16* __restrict__ Vt)
{
  __shared__ __align__(16) u16 T[64 * 72];
  const int t = threadIdx.x;
  const int st = blockIdx.x, bh = blockIdx.y;
  {
    const int r = t >> 2, c = (t & 3) * 16;
    const u16* src = &Vh[((size_t)bh * S_ + st * 64 + r) * DK + c];
    *reinterpret_cast<u16x8*>(&T[r * 72 + c])     = *reinterpret_cast<const u16x8*>(src);
    *reinterpret_cast<u16x8*>(&T[r * 72 + c + 8]) = *reinterpret_cast<const u16x8*>(src + 8);
  }
  __syncthreads();
  {
    const int d = t >> 2, s0 = (t & 3) * 16;
    u16x8 a, b;
    #pragma unroll
    for (int i = 0; i < 8; ++i) a[i] = T[(s0 + i) * 72 + d];
    #pragma unroll
    for (int i = 0; i < 8; ++i) b[i] = T[(s0 + 8 + i) * 72 + d];
    u16* dst = &Vt[((size_t)bh * DK + d) * S_ + st * 64 + s0];
    *reinterpret_cast<u16x8*>(dst)     = a;
    *reinterpret_cast<u16x8*>(dst + 8) = b;
  }
}

// ---------------------------------------------------------------------------
// Flash causal attention, 32x32x16 MFMA, QBLK=64, KVBLK=64, 2-WAVE BLOCKS.
// R5 (resubmit; previous bench was an infra failure, no data): R0-R4 evidence
// says per-iter time (~3900cyc) is a lockstep serial chain (ds_read->QK->SM->
// PV->barrier) with no co-resident work to hide stalls; the only config that
// ever overlapped was R0's 1024-block grid (22% occ, 1.19us/64q-iter). So:
// keep the lean R3/R4 inner loop, shrink the block to 64 q-rows / 2 waves /
// 128 threads, grid 1024 -> 4 independent blocks per CU (2 waves/SIMD),
// letting other blocks' MFMA/VALU fill this block's stalls.
//   - K: double-buffered via global_load_lds (16KB); V: single-buffer 8KB,
//     reg-staged with swizzled ds_write (both-sides rule). LDS 24.6KB/block.
//   - vmcnt(0) only after the tail barrier (loads fly over compute).
//   - Decode: XCD-grouped (4 heads/XCD), longest-first (qt=31-fid/32).
// ---------------------------------------------------------------------------
__global__ __launch_bounds__(128) void attn_kernel(
    const u16* __restrict__ Qh, const u16* __restrict__ Kh,
    const u16* __restrict__ Vt, float* __restrict__ out)
{
  __shared__ __align__(16) u16 Ks[2][64 * 64];   // [buf][key][dim]  (swizzled)
  __shared__ __align__(16) u16 Vs[64 * 64];      // [dim][key]       (swizzled)
  __shared__ float Ls[2][32];                    // per-wave 1/l

  const int tid  = threadIdx.x;
  const int lane = tid & 63;
  const int w    = tid >> 6;                     // wave 0/1 -> q-rows w*32..+31
  const int l31  = lane & 31, hi = lane >> 5;
  const int x7   = l31 & 7;

  // decode: xcd = fid&7 (4 heads per XCD); longest q-tiles dispatched first
  const int fid = blockIdx.x;
  const int bh  = (fid & 7) * 4 + ((fid >> 3) & 3);
  const int qt  = 31 - (fid >> 5);               // 32 q-tiles of 64 rows
  const int b   = bh >> 4, h = bh & 15;
  const int R0  = qt * 64;
  const int nt  = qt + 1;

  // Q as B-operand: B[k = s*16 + hi*8 + e][n = qrow = l31]
  bf16x8 qa[4];
  {
    const u16* qp = &Qh[((size_t)bh * S_ + R0 + w * 32 + l31) * DK + hi * 8];
    #pragma unroll
    for (int s = 0; s < 4; ++s)
      qa[s] = *reinterpret_cast<const bf16x8*>(qp + s * 16);
  }
  asm volatile("s_waitcnt vmcnt(0)" ::: "memory");   // clean vmcnt bookkeeping

  // staging: 512 chunks of 16B per 8KB tile; 128 threads x 4 passes.
  // chunk c = p*128+tid -> LDS (row=c>>3 = p*16 + (tid>>3), unit=c&7 = tid&7);
  // swizzled src/dst unit = (tid&7)^(row&7); (row&7) == ((tid>>3)&7) all passes.
  const u16* kb0 = Kh + (size_t)bh * S_ * DK;
  const u16* vb0 = Vt + (size_t)bh * DK * S_;
  const int rb8 = tid >> 3;                       // 0..15
  const int cs  = (tid & 7) ^ (rb8 & 7);
  const u16* sKp = kb0 + rb8 * DK + cs * 8;       // +1024/pass, +4096/tile
  const u16* sVp = vb0 + (size_t)rb8 * S_ + (tid & 7) * 8;  // +16*S_/pass, +64/tile
  u16* vdp = &Vs[rb8 * 64 + cs * 8];              // +1024/pass

  f32x16 oacc0 = {}, oacc1 = {};
  float lsum = 0.f;

  // prologue: V(0) -> regs, K(0) -> Ks[0]
  u16x8 vreg[4];
  #pragma unroll
  for (int p = 0; p < 4; ++p)
    vreg[p] = *reinterpret_cast<const u16x8*>(sVp + (size_t)p * 16 * S_);
  #pragma unroll
  for (int p = 0; p < 4; ++p)
    glds16(sKp + p * 1024, &Ks[0][(p * 128 + tid) * 8]);
  asm volatile("s_waitcnt vmcnt(0)" ::: "memory");

  int cur = 0;
  for (int t = 0; t < nt; ++t) {
    // A: publish V(t) regs -> Vs (swizzled; prev readers done at tail barrier)
    #pragma unroll
    for (int p = 0; p < 4; ++p)
      *reinterpret_cast<u16x8*>(vdp + p * 1024) = vreg[p];
    // B: prefetch t+1 (V->regs, K->Ks[cur^1]); in flight through compute(t)
    if (t + 1 < nt) {
      #pragma unroll
      for (int p = 0; p < 4; ++p)
        vreg[p] = *reinterpret_cast<const u16x8*>(
            sVp + (size_t)p * 16 * S_ + (t + 1) * 64);
      #pragma unroll
      for (int p = 0; p < 4; ++p)
        glds16(sKp + (size_t)(t + 1) * 4096 + p * 1024,
               &Ks[cur ^ 1][(p * 128 + tid) * 8]);
    }
    asm volatile("s_waitcnt lgkmcnt(0)" ::: "memory");  // V writes visible
    __builtin_amdgcn_s_barrier();
    asm volatile("" ::: "memory");

    const u16* Kb = Ks[cur];

    // causal geometry (wave-uniform): base = wave rowbase - tile keybase >= 0
    const int base  = R0 + w * 32 - t * 64;
    const int ksmax = (base + 31) >> 5;              // subtile ks live iff ks<=ksmax
    const int ksm   = (ksmax > 1) ? 1 : ksmax;

    {
      // ---- QK^T: S^T[key][qrow], 2 key-subtiles x 4 k-steps of 32x32x16
      f32x16 sfr[2];
      __builtin_amdgcn_s_setprio(1);
      #pragma unroll
      for (int ks = 0; ks < 2; ++ks) {
        if (ks > ksm) break;
        const int rb = (ks * 32 + l31) * 64;
        f32x16 sf = {};
        #pragma unroll
        for (int s = 0; s < 4; ++s) {
          const bf16x8 af = *reinterpret_cast<const bf16x8*>(
              &Kb[rb + ((2 * s + hi) ^ x7) * 8]);
          sf = __builtin_amdgcn_mfma_f32_32x32x16_bf16(af, qa[s], sf, 0, 0, 0);
        }
        sfr[ks] = sf;
      }
      __builtin_amdgcn_s_setprio(0);

      // ---- softmax (per-lane: lane owns qrow l31's scores) + pack
      unsigned pku[2][4][2];                         // [ks][m][word]
      #pragma unroll
      for (int ks = 0; ks < 2; ++ks) {
        if (ks > ksm) break;
        const int Dg = base + l31 - 32 * ks - 4 * hi;   // per-lane causal bound
        const bool full = (base >= 32 * ks + 31);       // wave-uniform: no mask
        float e[16];
        #pragma unroll
        for (int r = 0; r < 16; ++r) {
          const int rk = (r & 3) + 8 * (r >> 2);        // kloc minus 4*hi
          const float ex = __builtin_amdgcn_exp2f(sfr[ks][r]);
          e[r] = (full || rk <= Dg) ? ex : 0.f;
        }
        float a01 = 0.f;
        #pragma unroll
        for (int r = 0; r < 16; ++r) a01 += e[r];
        lsum += a01;
        #pragma unroll
        for (int m = 0; m < 4; ++m) {
          pku[ks][m][0] = cvtpk(e[4 * m], e[4 * m + 1]);
          pku[ks][m][1] = cvtpk(e[4 * m + 2], e[4 * m + 3]);
        }
      }

      // ---- PV: O[qrow][dim] += P x V. A-frags built in-register via swaps.
      const int smax = 2 * ksm + 1;
      #pragma unroll
      for (int s = 0; s < 4; ++s) {
        if (s > smax) break;
        const int ks = s >> 1, p = s & 1;
        unsigned w0 = pku[ks][2 * p][0],     w1v = pku[ks][2 * p][1];
        unsigned w2 = pku[ks][2 * p + 1][0], w3  = pku[ks][2 * p + 1][1];
        plswap(w0, w2);                              // -> words 0,2
        plswap(w1v, w3);                             // -> words 1,3
        u32x4 paw; paw[0] = w0; paw[1] = w1v; paw[2] = w2; paw[3] = w3;
        const bf16x8 pa = *reinterpret_cast<const bf16x8*>(&paw);
        const int uv = ((2 * s + hi) ^ x7) * 8;
        const bf16x8 vb0f = *reinterpret_cast<const bf16x8*>(&Vs[l31 * 64 + uv]);
        const bf16x8 vb1f = *reinterpret_cast<const bf16x8*>(&Vs[(32 + l31) * 64 + uv]);
        __builtin_amdgcn_s_setprio(1);
        oacc0 = __builtin_amdgcn_mfma_f32_32x32x16_bf16(pa, vb0f, oacc0, 0, 0, 0);
        oacc1 = __builtin_amdgcn_mfma_f32_32x32x16_bf16(pa, vb1f, oacc1, 0, 0, 0);
        __builtin_amdgcn_s_setprio(0);
      }
    }

    asm volatile("" ::: "memory");
    __builtin_amdgcn_s_barrier();                    // Ks[cur]/Vs free for re-stage
    asm volatile("s_waitcnt vmcnt(0)" ::: "memory"); // t+1 loads landed (flew over E)
    cur ^= 1;
  }

  // epilogue: qrow sums live per-lane (col side); redistribute via tiny LDS
  const float lt = lsum + __shfl_xor(lsum, 32, 64);
  if (hi == 0) Ls[w][l31] = 1.0f / lt;
  // oacc row r -> qrow-within-32 = (r&3)+8*(r>>2)+4*hi ; col = dim = ds*32+l31
  #pragma unroll
  for (int r = 0; r < 16; ++r) {
    const int rq = (r & 3) + 8 * (r >> 2) + 4 * hi;
    const float inv = Ls[w][rq];
    const int srow = R0 + w * 32 + rq;
    float* op = &out[(size_t)(b * S_ + srow) * DM + h * DK + l31];
    op[0]  = oacc0[r] * inv;
    op[32] = oacc1[r] * inv;
  }
}

extern "C" void kernel_launch(void* const* d_in, const int* in_sizes, int n_in,
                              void* d_out, int out_size, void* d_ws, size_t ws_size,
                              hipStream_t stream) {
  // inputs: q,k,v,mask,Wq,bq,Wk,bk,Wv,bv — fp32 (mask int32, unused)
  const float* q  = (const float*)d_in[0];
  const float* k  = (const float*)d_in[1];
  const float* v  = (const float*)d_in[2];
  const float* Wq = (const float*)d_in[4];
  const float* bq = (const float*)d_in[5];
  const float* Wk = (const float*)d_in[6];
  const float* bk = (const float*)d_in[7];
  const float* Wv = (const float*)d_in[8];
  const float* bv = (const float*)d_in[9];

  u16* Xq  = (u16*)d_ws;          // 8 MB each for X*, 2 MB each for W*
  u16* Xk  = Xq + NX;
  u16* Xv  = Xk + NX;
  u16* Wqb = Xv + NX;
  u16* Wkb = Wqb + NW;
  u16* Wvb = Wkb + NW;
  u16* Qh  = Wvb + NW;            // [bh][s][d]
  u16* Kh  = Qh + NX;             // [bh][s][d]
  u16* Vh  = Kh + NX;             // [bh][s][d]
  u16* Vt  = Xq;                  // [bh][d][s] — aliases Xq (dead after proj)

  cvt_kernel<<<dim3(NX / (256 * 8), 6), 256, 0, stream>>>(
      q, k, v, Wq, Wk, Wv, Xq, Xk, Xv, Wqb, Wkb, Wvb);
  proj_kernel<<<dim3(DM / 128, (B_ * S_) / 128, 3), 256, 0, stream>>>(
      Xq, Xk, Xv, Wqb, Wkb, Wvb, bq, bk, bv, Qh, Kh, Vh);
  transpose_kernel<<<dim3(S_ / 64, B_ * H_), 256, 0, stream>>>(Vh, Vt);
  attn_kernel<<<dim3(1024), 128, 0, stream>>>(
      Qh, Kh, Vt, (float*)d_out);
}

// Round 7
// 207.240 us; speedup vs baseline: 1.0584x; 1.0568x over previous
//
#include <hip/hip_runtime.h>

#define B_ 2
#define H_ 16
#define S_ 2048
#define DM 1024
#define DK 64
#define NX (4096 * 1024)   // q/k/v element count
#define NW (1024 * 1024)   // W element count

typedef unsigned short u16;
typedef __attribute__((ext_vector_type(8))) short bf16x8;          // MFMA A/B frag
typedef __attribute__((ext_vector_type(8))) unsigned short u16x8;  // 16-byte unit
typedef __attribute__((ext_vector_type(4))) unsigned short u16x4;  // 8-byte unit
typedef __attribute__((ext_vector_type(2))) unsigned int u32x2;    // 8-byte unit
typedef __attribute__((ext_vector_type(4))) float f32x4;           // MFMA C/D

__device__ inline u16 f2bf(float f) {                       // RNE float->bf16
  union { float f; unsigned int u; } c; c.f = f;
  unsigned int u = c.u;
  u += 0x7fffu + ((u >> 16) & 1u);
  return (u16)(u >> 16);
}

__device__ inline u16x8 cvt8(const float* __restrict__ src) {
  const float4 a = *reinterpret_cast<const float4*>(src);
  const float4 b = *reinterpret_cast<const float4*>(src + 4);
  u16x8 r;
  r[0] = f2bf(a.x); r[1] = f2bf(a.y); r[2] = f2bf(a.z); r[3] = f2bf(a.w);
  r[4] = f2bf(b.x); r[5] = f2bf(b.y); r[6] = f2bf(b.z); r[7] = f2bf(b.w);
  return r;
}

__device__ inline void glds16(const u16* g, u16* l) {       // async global->LDS, 16B/lane
  __builtin_amdgcn_global_load_lds(
      (const __attribute__((address_space(1))) unsigned int*)g,
      (__attribute__((address_space(3))) unsigned int*)l, 16, 0, 0);
}

__device__ inline unsigned cvtpk(float lo, float hi) {      // pack 2xf32 -> 2xbf16 (RNE)
  unsigned r;
  asm("v_cvt_pk_bf16_f32 %0, %1, %2" : "=v"(r) : "v"(lo), "v"(hi));
  return r;
}

// ---------------------------------------------------------------------------
// Prepass: fp32 -> bf16 once per tensor.
// ---------------------------------------------------------------------------
__global__ __launch_bounds__(256) void cvt_kernel(
    const float* __restrict__ q, const float* __restrict__ k, const float* __restrict__ v,
    const float* __restrict__ Wq, const float* __restrict__ Wk, const float* __restrict__ Wv,
    u16* __restrict__ Xq, u16* __restrict__ Xk, u16* __restrict__ Xv,
    u16* __restrict__ Wqb, u16* __restrict__ Wkb, u16* __restrict__ Wvb)
{
  const int t = blockIdx.y;
  const float* src = (t == 0) ? q : (t == 1) ? k : (t == 2) ? v
                   : (t == 3) ? Wq : (t == 4) ? Wk : Wv;
  u16* dst = (t == 0) ? Xq : (t == 1) ? Xk : (t == 2) ? Xv
           : (t == 3) ? Wqb : (t == 4) ? Wkb : Wvb;
  const int n = (t < 3) ? NX : NW;
  const int idx = (blockIdx.x * 256 + threadIdx.x) * 8;
  if (idx >= n) return;
  *reinterpret_cast<u16x8*>(&dst[idx]) = cvt8(&src[idx]);
}

// ---------------------------------------------------------------------------
// Projection: Y = X @ W^T + b (bf16, m97-style). ALL outputs [bh][s][d].
// z=0 (Q) pre-scaled by (1/sqrt(Dk))*log2(e) for exp2 softmax.
// R7: XCD-locality swizzle (T1). 1D grid of 768; xcd = bid&7 owns a 4-row
// y-stripe for all j,z. Per-XCD working set per j-sweep = 256KB X-tile +
// 2MB W < 4MB L2 -> X fetched ~once/XCD, W ~once/XCD/z.
// ---------------------------------------------------------------------------
__global__ __launch_bounds__(256) void proj_kernel(
    const u16* __restrict__ Xq, const u16* __restrict__ Xk, const u16* __restrict__ Xv,
    const u16* __restrict__ Wqb, const u16* __restrict__ Wkb, const u16* __restrict__ Wvb,
    const float* __restrict__ bq, const float* __restrict__ bk, const float* __restrict__ bv,
    u16* __restrict__ Qh, u16* __restrict__ Kh, u16* __restrict__ Vh)
{
  // decode: bid -> (xcd, z, y-stripe row, j)
  const int bid = blockIdx.x;
  const int xcd = bid & 7;
  const int tt  = bid >> 3;          // 0..95 per XCD
  const int z   = tt >> 5;           // 0..2
  const int rr  = tt & 31;
  const int by  = xcd * 4 + (rr >> 3);   // 0..31 (4-row stripe per XCD)
  const int bj  = rr & 7;                // 0..7

  const u16* X      = (z == 0) ? Xq : (z == 1) ? Xk : Xv;
  const u16* W      = (z == 0) ? Wqb : (z == 1) ? Wkb : Wvb;
  const float* bias = (z == 0) ? bq : (z == 1) ? bk : bv;
  u16* out          = (z == 0) ? Qh : (z == 1) ? Kh : Vh;
  const float scale = (z == 0) ? 0.18033688f : 1.0f;   // 0.125 * log2(e)

  __shared__ __align__(16) u16 Xs[128 * 32];   // unpadded: required by global_load_lds
  __shared__ __align__(16) u16 Ws[128 * 32];

  const int tid = threadIdx.x;
  const int lane = tid & 63;
  const int w = tid >> 6;
  const int wy = w >> 1, wx = w & 1;
  const int m0 = by * 128;
  const int n0 = bj * 128;
  const int ml = lane & 15;
  const int qd = lane >> 4;

  f32x4 acc[4][4] = {};

  for (int kb = 0; kb < DM; kb += 32) {
    __syncthreads();
    #pragma unroll
    for (int p = 0; p < 2; ++p) {
      const int c = p * 4 + w;                  // chunk: 16 rows x 32 cols = 1 KiB
      const int row = c * 16 + (lane >> 2);
      const int col = kb + (lane & 3) * 8;
      glds16(&X[(size_t)(m0 + row) * DM + col], &Xs[c * 512]);
      glds16(&W[(size_t)(n0 + row) * DM + col], &Ws[c * 512]);
    }
    __syncthreads();
    bf16x8 a[4], bfr[4];
    #pragma unroll
    for (int i = 0; i < 4; ++i)
      a[i] = *reinterpret_cast<const bf16x8*>(&Xs[(wy * 64 + i * 16 + ml) * 32 + qd * 8]);
    #pragma unroll
    for (int j = 0; j < 4; ++j)
      bfr[j] = *reinterpret_cast<const bf16x8*>(&Ws[(wx * 64 + j * 16 + ml) * 32 + qd * 8]);
    #pragma unroll
    for (int i = 0; i < 4; ++i)
      #pragma unroll
      for (int j = 0; j < 4; ++j)
        acc[i][j] = __builtin_amdgcn_mfma_f32_16x16x32_bf16(a[i], bfr[j], acc[i][j], 0, 0, 0);
  }

  #pragma unroll
  for (int j = 0; j < 4; ++j) {
    const int n = n0 + wx * 64 + j * 16 + ml;
    const float badd = bias[n];
    const int h = n >> 6, d = n & 63;
    #pragma unroll
    for (int i = 0; i < 4; ++i) {
      #pragma unroll
      for (int r = 0; r < 4; ++r) {
        const int m = m0 + wy * 64 + i * 16 + qd * 4 + r;
        const int bi = m >> 11, s = m & 2047;
        out[((bi * H_ + h) * S_ + s) * DK + d] = f2bf((acc[i][j][r] + badd) * scale);
      }
    }
  }
}

// ---------------------------------------------------------------------------
// Vh[bh][s][d] -> Vt[bh][d][s]  (64x64 LDS tile transpose, coalesced both ways)
// ---------------------------------------------------------------------------
__global__ __launch_bounds__(256) void transpose_kernel(
    const u16* __restrict__ Vh, u16* __restrict__ Vt)
{
  __shared__ __align__(16) u16 T[64 * 72];
  const int t = threadIdx.x;
  const int st = blockIdx.x, bh = blockIdx.y;
  {
    const int r = t >> 2, c = (t & 3) * 16;
    const u16* src = &Vh[((size_t)bh * S_ + st * 64 + r) * DK + c];
    *reinterpret_cast<u16x8*>(&T[r * 72 + c])     = *reinterpret_cast<const u16x8*>(src);
    *reinterpret_cast<u16x8*>(&T[r * 72 + c + 8]) = *reinterpret_cast<const u16x8*>(src + 8);
  }
  __syncthreads();
  {
    const int d = t >> 2, s0 = (t & 3) * 16;
    u16x8 a, b;
    #pragma unroll
    for (int i = 0; i < 8; ++i) a[i] = T[(s0 + i) * 72 + d];
    #pragma unroll
    for (int i = 0; i < 8; ++i) b[i] = T[(s0 + 8 + i) * 72 + d];
    u16* dst = &Vt[((size_t)bh * DK + d) * S_ + st * 64 + s0];
    *reinterpret_cast<u16x8*>(dst)     = a;
    *reinterpret_cast<u16x8*>(dst + 8) = b;
  }
}

// ---------------------------------------------------------------------------
// Flash causal attention — R1 version VERBATIM (best measured: 53.1 µs).
// QBLK=128, KVBLK=64, 4 waves; wave owns 32 q-rows (two 16-row groups).
// K/V double-buffered via global_load_lds, counted vmcnt(4), raw barriers;
// S^T formulation, per-lane softmax (exp2, scale folded in Q), P packed via
// cvt_pk to per-wave Ps (LDS round-trip); balanced co-resident qt pairing.
// ---------------------------------------------------------------------------
__global__ __launch_bounds__(256) void attn_kernel(
    const u16* __restrict__ Qh, const u16* __restrict__ Kh,
    const u16* __restrict__ Vt, float* __restrict__ out)
{
  __shared__ __align__(16) u16 Ks[2][64 * 64];   // [buf][key][dim]   (swizzled)
  __shared__ __align__(16) u16 Vs[2][64 * 64];   // [buf][dim][key]   (swizzled)
  __shared__ __align__(16) u16 Ps[4][2][16 * 64];// [wave][g][qrow][key] (swizzled)

  const int tid  = threadIdx.x;
  const int lane = tid & 63;
  const int w    = tid >> 6;

  const int fid = blockIdx.x;
  const int bh  = (fid & 7) * 4 + ((fid >> 3) & 3);
  const int qt  = 15 - (fid >> 5);
  const int b   = bh >> 4, h = bh & 15;
  const int ml  = lane & 15, qd = lane >> 4;
  const int m7  = ml & 7;
  const int u0  = qd ^ m7;               // swizzled 16B-col base for frag reads
  const int qh  = qd >> 1, ql = qd & 1;
  const int R0  = qt * 128;
  const int nt  = 2 * qt + 2;            // # of 64-key tiles

  // Q as B-operand: B[k=dim][n=qrow=ml]; 2 groups x 2 dim-chunks
  bf16x8 qa[2][2];
  #pragma unroll
  for (int g = 0; g < 2; ++g)
    #pragma unroll
    for (int ch = 0; ch < 2; ++ch)
      qa[g][ch] = *reinterpret_cast<const bf16x8*>(
          &Qh[((size_t)bh * S_ + R0 + w * 32 + g * 16 + ml) * DK + ch * 32 + qd * 8]);
  // drain Q loads so manual vmcnt bookkeeping below counts only glds16 ops
  asm volatile("s_waitcnt vmcnt(0)" ::: "memory");

  // staging: 512 16B-chunks per 8KB tile; thread stages chunks tid and tid+256.
  // chunk c -> LDS (row=c>>3, col'=c&7); global source col = (c&7) ^ (row&7)
  const u16* kb0 = Kh + (size_t)bh * S_ * DK;
  const u16* vb0 = Vt + (size_t)bh * DK * S_;
  const int r0 = tid >> 3, r1 = r0 + 32;         // (tid+256)>>3 = r0+32
  const int cs = (tid & 7) ^ (r0 & 7);           // (r1&7)==(r0&7)
  const u16* sK0 = kb0 + r0 * DK + cs * 8;       // advance +4096/tile (64 rows)
  const u16* sK1 = kb0 + r1 * DK + cs * 8;
  const u16* sV0 = vb0 + (size_t)r0 * S_ + cs * 8;  // advance +64/tile (64 keys)
  const u16* sV1 = vb0 + (size_t)r1 * S_ + cs * 8;

  f32x4 oacc[2][4] = {};
  float lsum[2] = {0.f, 0.f};

  // prologue: stage tile 0 into buf 0 (4 glds16 per wave)
  glds16(sK0, &Ks[0][tid * 8]);
  glds16(sK1, &Ks[0][2048 + tid * 8]);
  glds16(sV0, &Vs[0][tid * 8]);
  glds16(sV1, &Vs[0][2048 + tid * 8]);
  sK0 += 4096; sK1 += 4096; sV0 += 64; sV1 += 64;

  int cur = 0;
  for (int t = 0; t < nt; ++t) {
    if (t + 1 < nt) {                            // issue next tile, then wait
      glds16(sK0, &Ks[cur ^ 1][tid * 8]);        // for CURRENT tile only: 4
      glds16(sK1, &Ks[cur ^ 1][2048 + tid * 8]); // newest loads stay in flight
      glds16(sV0, &Vs[cur ^ 1][tid * 8]);
      glds16(sV1, &Vs[cur ^ 1][2048 + tid * 8]);
      sK0 += 4096; sK1 += 4096; sV0 += 64; sV1 += 64;
      asm volatile("s_waitcnt vmcnt(4)" ::: "memory");
    } else {
      asm volatile("s_waitcnt vmcnt(0)" ::: "memory");
    }
    __builtin_amdgcn_s_barrier();
    asm volatile("" ::: "memory");

    const u16* Kb = Ks[cur];
    const u16* Vb = Vs[cur];

    // wave-uniform causal geometry: d16g = (rowbase - t*64)/16
    const int d16_0 = (R0 + w * 32 - t * 64) >> 4;
    const int d16_1 = d16_0 + 1;
    const int jtop  = (d16_1 < 3) ? d16_1 : 3;

    if (jtop >= 0) {
      #pragma unroll
      for (int j = 0; j < 4; ++j) {
        if (j > jtop) break;
        const int rk = (j * 16 + ml) * 64;
        const bf16x8 k0 = *reinterpret_cast<const bf16x8*>(&Kb[rk + u0 * 8]);
        const bf16x8 k1 = *reinterpret_cast<const bf16x8*>(&Kb[rk + (u0 ^ 4) * 8]);
        #pragma unroll
        for (int g = 0; g < 2; ++g) {
          const int d16g = d16_0 + g;
          if (j > d16g) continue;                // wave-uniform
          f32x4 zz = {};
          zz = __builtin_amdgcn_mfma_f32_16x16x32_bf16(k0, qa[g][0], zz, 0, 0, 0);
          zz = __builtin_amdgcn_mfma_f32_16x16x32_bf16(k1, qa[g][1], zz, 0, 0, 0);
          if (j == d16g) {                       // diagonal subtile mask
            #pragma unroll
            for (int r = 0; r < 4; ++r)
              if (qd * 4 + r > ml) zz[r] = -1e30f;
          }
          const float e0 = __builtin_amdgcn_exp2f(zz[0]);
          const float e1 = __builtin_amdgcn_exp2f(zz[1]);
          const float e2 = __builtin_amdgcn_exp2f(zz[2]);
          const float e3 = __builtin_amdgcn_exp2f(zz[3]);
          lsum[g] += (e0 + e1) + (e2 + e3);
          u32x2 pk;
          pk[0] = cvtpk(e0, e1);
          pk[1] = cvtpk(e2, e3);
          *reinterpret_cast<u32x2*>(
              &Ps[w][g][ml * 64 + (((2 * j + qh) ^ m7) * 8) + ql * 4]) = pk;
        }
      }
      // zero-fill P subtiles covered by an active PV chunk but fully masked
      #pragma unroll
      for (int g = 0; g < 2; ++g) {
        const int d16g = d16_0 + g;
        if (d16g == 0 || d16g == 2) {
          const int jz = d16g + 1;
          *reinterpret_cast<u32x2*>(
              &Ps[w][g][ml * 64 + (((2 * jz + qh) ^ m7) * 8) + ql * 4]) = (u32x2){0, 0};
        }
      }
      // O += P V : A=P (per-wave Ps), B=V^T; V frags reused across both groups
      #pragma unroll
      for (int c = 0; c < 2; ++c) {
        const bool use0 = d16_0 >= 2 * c;
        const bool use1 = d16_1 >= 2 * c;
        if (!(use0 | use1)) continue;            // wave-uniform
        bf16x8 vb[4];
        #pragma unroll
        for (int dj = 0; dj < 4; ++dj)
          vb[dj] = *reinterpret_cast<const bf16x8*>(
              &Vb[(dj * 16 + ml) * 64 + (u0 ^ (c << 2)) * 8]);
        if (use0) {
          const bf16x8 pa = *reinterpret_cast<const bf16x8*>(
              &Ps[w][0][ml * 64 + (u0 ^ (c << 2)) * 8]);
          #pragma unroll
          for (int dj = 0; dj < 4; ++dj)
            oacc[0][dj] = __builtin_amdgcn_mfma_f32_16x16x32_bf16(pa, vb[dj], oacc[0][dj], 0, 0, 0);
        }
        if (use1) {
          const bf16x8 pa = *reinterpret_cast<const bf16x8*>(
              &Ps[w][1][ml * 64 + (u0 ^ (c << 2)) * 8]);
          #pragma unroll
          for (int dj = 0; dj < 4; ++dj)
            oacc[1][dj] = __builtin_amdgcn_mfma_f32_16x16x32_bf16(pa, vb[dj], oacc[1][dj], 0, 0, 0);
        }
      }
    }

    asm volatile("" ::: "memory");
    __builtin_amdgcn_s_barrier();                // buf[cur] free for re-stage
    asm volatile("" ::: "memory");
    cur ^= 1;
  }

  // epilogue: complete row-sums across quads, normalize, store fp32
  #pragma unroll
  for (int g = 0; g < 2; ++g) {
    float lg = lsum[g];
    lg += __shfl_xor(lg, 16, 64);
    lg += __shfl_xor(lg, 32, 64);
    #pragma unroll
    for (int r = 0; r < 4; ++r) {
      const float inv = 1.0f / __shfl(lg, qd * 4 + r, 64);
      const int srow = R0 + w * 32 + g * 16 + qd * 4 + r;
      float* op = &out[(size_t)(b * S_ + srow) * DM + h * DK + ml];
      #pragma unroll
      for (int dj = 0; dj < 4; ++dj)
        op[dj * 16] = oacc[g][dj][r] * inv;
    }
  }
}

extern "C" void kernel_launch(void* const* d_in, const int* in_sizes, int n_in,
                              void* d_out, int out_size, void* d_ws, size_t ws_size,
                              hipStream_t stream) {
  // inputs: q,k,v,mask,Wq,bq,Wk,bk,Wv,bv — fp32 (mask int32, unused)
  const float* q  = (const float*)d_in[0];
  const float* k  = (const float*)d_in[1];
  const float* v  = (const float*)d_in[2];
  const float* Wq = (const float*)d_in[4];
  const float* bq = (const float*)d_in[5];
  const float* Wk = (const float*)d_in[6];
  const float* bk = (const float*)d_in[7];
  const float* Wv = (const float*)d_in[8];
  const float* bv = (const float*)d_in[9];

  u16* Xq  = (u16*)d_ws;          // 8 MB each for X*, 2 MB each for W*
  u16* Xk  = Xq + NX;
  u16* Xv  = Xk + NX;
  u16* Wqb = Xv + NX;
  u16* Wkb = Wqb + NW;
  u16* Wvb = Wkb + NW;
  u16* Qh  = Wvb + NW;            // [bh][s][d]
  u16* Kh  = Qh + NX;             // [bh][s][d]
  u16* Vh  = Kh + NX;             // [bh][s][d]
  u16* Vt  = Xq;                  // [bh][d][s] — aliases Xq (dead after proj)

  cvt_kernel<<<dim3(NX / (256 * 8), 6), 256, 0, stream>>>(
      q, k, v, Wq, Wk, Wv, Xq, Xk, Xv, Wqb, Wkb, Wvb);
  proj_kernel<<<dim3(768), 256, 0, stream>>>(
      Xq, Xk, Xv, Wqb, Wkb, Wvb, bq, bk, bv, Qh, Kh, Vh);
  transpose_kernel<<<dim3(S_ / 64, B_ * H_), 256, 0, stream>>>(Vh, Vt);
  attn_kernel<<<dim3(512), 256, 0, stream>>>(
      Qh, Kh, Vt, (float*)d_out);
}